// Round 8
// baseline (271.197 us; speedup 1.0000x reference)
//
#include <hip/hip_runtime.h>

typedef __attribute__((ext_vector_type(8))) short s8v;
typedef __attribute__((ext_vector_type(4))) float f4;
typedef __attribute__((ext_vector_type(4))) unsigned u4v;

#define SEQ 1024
#define BATCH 2048
#define SLOT 4
#define NSLOT (SEQ / SLOT + 3)   // 259

// Split (a,b) into bf16 hi-plane word and bf16 lo-plane (residual) word.
// hi word: low16 = a[31:16], high16 = b[31:16] — one v_perm_b32.
// (If the builtin's operand order were swapped, the SAME permutation applies
// to A- and B-fragments alike, so the MFMA product is invariant.)
__device__ __forceinline__ void splitpk(float a, float b, unsigned &hw, unsigned &lw) {
  unsigned au = __float_as_uint(a), bu = __float_as_uint(b);
  hw = __builtin_amdgcn_perm(bu, au, 0x07060302u);
  float la = a - __uint_as_float(au & 0xffff0000u);
  float lb = b - __uint_as_float(bu & 0xffff0000u);
  lw = __builtin_amdgcn_perm(__float_as_uint(lb), __float_as_uint(la), 0x07060302u);
}

__device__ __forceinline__ f4 MF(const unsigned (&a)[4], const unsigned (&b)[4], f4 c) {
  union U { unsigned u[4]; s8v v; } A, B;
  A.u[0] = a[0]; A.u[1] = a[1]; A.u[2] = a[2]; A.u[3] = a[3];
  B.u[0] = b[0]; B.u[1] = b[1]; B.u[2] = b[2]; B.u[3] = b[3];
  return __builtin_amdgcn_mfma_f32_16x16x32_bf16(A.v, B.v, c, 0, 0, 0);
}

// k-map (same on A and B operands so any mismatch with the true HW map
// cancels): elem i of lane-group g -> k = 4g+i (i<4), k = 16+4g+(i-4) (i>=4).
// C-layout (row = 4g + reg) feeds the next B-fragment with NO cross-lane moves.

__device__ __forceinline__ void conv(f4 va, f4 vb, unsigned (&hi)[4], unsigned (&lo)[4]) {
  splitpk(va[0], va[1], hi[0], lo[0]);
  splitpk(va[2], va[3], hi[1], lo[1]);
  splitpk(vb[0], vb[1], hi[2], lo[2]);
  splitpk(vb[2], vb[3], hi[3], lo[3]);
}

__device__ __forceinline__ void loadA(const float* W, int row, int g,
                                      unsigned (&hi)[4], unsigned (&lo)[4]) {
  const float* p = W + row * 32;
  f4 u = *(const f4*)(p + 4 * g);
  f4 v = *(const f4*)(p + 16 + 4 * g);
  splitpk(u[0], u[1], hi[0], lo[0]);
  splitpk(u[2], u[3], hi[1], lo[1]);
  splitpk(v[0], v[1], hi[2], lo[2]);
  splitpk(v[2], v[3], hi[3], lo[3]);
}

// 4-wave feed-forward pipeline, 4 timesteps per slot, 1 barrier per slot.
//   wave 0 (A): h1 recurrence (in regs)          -> LH1[m&1]
//   wave 1 (D): P = Wih1@h1 + b1 (feed-forward)  -> LP [m&1]
//   wave 2 (B): h2 = relu(P + Whh1@h2) (in regs) -> LB2[m&1]
//   wave 3 (C): out = Wout.h2 + bO
// Skews: A slots [0,255], D [1,256], B [2,257], C [3,258].
__global__ __launch_bounds__(256) void rnn_fused(
    const float* __restrict__ x,    const float* __restrict__ h0,
    const float* __restrict__ Wih0, const float* __restrict__ Whh0,
    const float* __restrict__ bih0, const float* __restrict__ bhh0,
    const float* __restrict__ Wih1, const float* __restrict__ Whh1,
    const float* __restrict__ bih1, const float* __restrict__ bhh1,
    const float* __restrict__ Wout, const float* __restrict__ boutp,
    float* __restrict__ out)
{
  const int tid  = threadIdx.x;
  const int wid  = tid >> 6;
  const int lane = tid & 63;
  const int c = lane & 15;      // batch column within tile (also A-frag row)
  const int g = lane >> 4;      // lane group 0..3
  const int b = blockIdx.x * 16 + c;
  const unsigned li = (unsigned)lane * 4u;

  // All planes are b128-per-lane at lane*16B — the conflict-minimal pattern.
  __shared__ unsigned LH1[2][SLOT][2][256];  // [parity][step j][hi/lo][u32]
  __shared__ float    LP [2][SLOT][2][256];  // [parity][step j][P0/P1][f32]
  __shared__ unsigned LB2[2][SLOT][2][256];  // [parity][step j][hi/lo][u32]

  const f4 z = {0.f, 0.f, 0.f, 0.f};
  float* hs = out + SEQ * BATCH;

  if (wid == 0) {
    // ================= WAVE A : layer 0 (h1 recurrence) =================
    unsigned W00h[4], W00l[4], W01h[4], W01l[4];
    loadA(Whh0, c,      g, W00h, W00l);
    loadA(Whh0, 16 + c, g, W01h, W01l);
    f4 wih0A, wih0B, b0A, b0B;
#pragma unroll
    for (int r = 0; r < 4; ++r) {
      int j0 = 4 * g + r, j1 = 16 + 4 * g + r;
      wih0A[r] = Wih0[j0];            wih0B[r] = Wih0[j1];
      b0A[r]   = bih0[j0] + bhh0[j0]; b0B[r]   = bih0[j1] + bhh0[j1];
    }
    unsigned B1h[4], B1l[4];
    {
      const float* p1 = h0 + b * 32;
      f4 u = *(const f4*)(p1 + 4 * g);
      f4 v = *(const f4*)(p1 + 16 + 4 * g);
      splitpk(u[0], u[1], B1h[0], B1l[0]);
      splitpk(u[2], u[3], B1h[1], B1l[1]);
      splitpk(v[0], v[1], B1h[2], B1l[2]);
      splitpk(v[2], v[3], B1h[3], B1l[3]);
    }
    f4 v10 = z, v11 = z;
    float xc[SLOT];
#pragma unroll
    for (int j = 0; j < SLOT; ++j) xc[j] = x[j * BATCH + b];

#pragma unroll 1
    for (int m = 0; m < NSLOT; ++m) {
      if (m < SEQ / SLOT) {
        float xn[SLOT];
#pragma unroll
        for (int j = 0; j < SLOT; ++j) {
          int ti = SLOT * m + SLOT + j;
          xn[j] = x[(ti < SEQ ? ti : SEQ - 1) * BATCH + b];
        }
#pragma unroll
        for (int j = 0; j < SLOT; ++j) {
          float XV = xc[j];
          f4 cx0, cx1;
#pragma unroll
          for (int r = 0; r < 4; ++r) {
            cx0[r] = fmaf(XV, wih0A[r], b0A[r]);
            cx1[r] = fmaf(XV, wih0B[r], b0B[r]);
          }
          // INDEPENDENT plane-MFMAs (no C-chain); fp32 tree-sum.
          f4 p0 = MF(W00h, B1h, z);
          f4 p1 = MF(W00h, B1l, z);
          f4 p2 = MF(W00l, B1h, z);
          f4 q0 = MF(W01h, B1h, z);
          f4 q1 = MF(W01h, B1l, z);
          f4 q2 = MF(W01l, B1h, z);
#pragma unroll
          for (int r = 0; r < 4; ++r) {
            v10[r] = fmaxf((cx0[r] + p0[r]) + (p1[r] + p2[r]), 0.f);
            v11[r] = fmaxf((cx1[r] + q0[r]) + (q1[r] + q2[r]), 0.f);
          }
          conv(v10, v11, B1h, B1l);
          u4v wh = { B1h[0], B1h[1], B1h[2], B1h[3] };
          u4v wl = { B1l[0], B1l[1], B1l[2], B1l[3] };
          *(u4v*)&LH1[m & 1][j][0][li] = wh;
          *(u4v*)&LH1[m & 1][j][1][li] = wl;
        }
#pragma unroll
        for (int j = 0; j < SLOT; ++j) xc[j] = xn[j];
      }
      __syncthreads();
    }
    *(f4*)(hs + b * 32 + 4 * g)      = v10;   // h1_SEQ
    *(f4*)(hs + b * 32 + 16 + 4 * g) = v11;

  } else if (wid == 1) {
    // ========== WAVE D : feeder P = Wih1 @ h1 + b1 (full 32 rows) ==========
    unsigned WiH0[4], WiL0[4], WiH1[4], WiL1[4];
    loadA(Wih1, c,      g, WiH0, WiL0);
    loadA(Wih1, 16 + c, g, WiH1, WiL1);
    f4 b1A, b1B;
#pragma unroll
    for (int r = 0; r < 4; ++r) {
      int j0 = 4 * g + r, j1 = 16 + 4 * g + r;
      b1A[r] = bih1[j0] + bhh1[j0];
      b1B[r] = bih1[j1] + bhh1[j1];
    }

#pragma unroll 1
    for (int m = 0; m < NSLOT; ++m) {
      if (m >= 1 && m <= SEQ / SLOT) {
        int p = (m - 1) & 1;
        u4v fh[SLOT], fl[SLOT];
#pragma unroll
        for (int j = 0; j < SLOT; ++j) {
          fh[j] = *(const u4v*)&LH1[p][j][0][li];
          fl[j] = *(const u4v*)&LH1[p][j][1][li];
        }
#pragma unroll
        for (int j = 0; j < SLOT; ++j) {
          unsigned B1h[4] = { fh[j][0], fh[j][1], fh[j][2], fh[j][3] };
          unsigned B1l[4] = { fl[j][0], fl[j][1], fl[j][2], fl[j][3] };
          f4 p0 = MF(WiH0, B1h, b1A);
          f4 p1 = MF(WiH0, B1l, z);
          f4 p2 = MF(WiL0, B1h, z);
          f4 q0 = MF(WiH1, B1h, b1B);
          f4 q1 = MF(WiH1, B1l, z);
          f4 q2 = MF(WiL1, B1h, z);
          f4 P0, P1;
#pragma unroll
          for (int r = 0; r < 4; ++r) {
            P0[r] = p0[r] + p1[r] + p2[r];
            P1[r] = q0[r] + q1[r] + q2[r];
          }
          *(f4*)&LP[m & 1][j][0][li] = P0;
          *(f4*)&LP[m & 1][j][1][li] = P1;
        }
      }
      __syncthreads();
    }

  } else if (wid == 2) {
    // ========== WAVE B : h2 recurrence = relu(P + Whh1 @ h2) ==========
    unsigned WhH0[4], WhL0[4], WhH1[4], WhL1[4];
    loadA(Whh1, c,      g, WhH0, WhL0);
    loadA(Whh1, 16 + c, g, WhH1, WhL1);
    unsigned B2h[4], B2l[4];
    f4 v20 = z, v21 = z;
    {
      const float* p2 = h0 + BATCH * 32 + b * 32;
      f4 u = *(const f4*)(p2 + 4 * g);
      f4 v = *(const f4*)(p2 + 16 + 4 * g);
      splitpk(u[0], u[1], B2h[0], B2l[0]);
      splitpk(u[2], u[3], B2h[1], B2l[1]);
      splitpk(v[0], v[1], B2h[2], B2l[2]);
      splitpk(v[2], v[3], B2h[3], B2l[3]);
      v20 = u; v21 = v;
    }

#pragma unroll 1
    for (int m = 0; m < NSLOT; ++m) {
      if (m >= 2 && m <= SEQ / SLOT + 1) {
        int p = (m - 1) & 1;
        f4 Pa[SLOT], Pb[SLOT];
#pragma unroll
        for (int j = 0; j < SLOT; ++j) {
          Pa[j] = *(const f4*)&LP[p][j][0][li];
          Pb[j] = *(const f4*)&LP[p][j][1][li];
        }
#pragma unroll
        for (int j = 0; j < SLOT; ++j) {
          f4 r0 = MF(WhH0, B2h, Pa[j]);
          f4 r1 = MF(WhH0, B2l, z);
          f4 r2 = MF(WhL0, B2h, z);
          f4 s0 = MF(WhH1, B2h, Pb[j]);
          f4 s1 = MF(WhH1, B2l, z);
          f4 s2 = MF(WhL1, B2h, z);
#pragma unroll
          for (int r = 0; r < 4; ++r) {
            v20[r] = fmaxf(r0[r] + r1[r] + r2[r], 0.f);
            v21[r] = fmaxf(s0[r] + s1[r] + s2[r], 0.f);
          }
          conv(v20, v21, B2h, B2l);
          u4v wh = { B2h[0], B2h[1], B2h[2], B2h[3] };
          u4v wl = { B2l[0], B2l[1], B2l[2], B2l[3] };
          *(u4v*)&LB2[m & 1][j][0][li] = wh;
          *(u4v*)&LB2[m & 1][j][1][li] = wl;
        }
      }
      __syncthreads();
    }
    *(f4*)(hs + BATCH * 32 + b * 32 + 4 * g)      = v20;  // h2_SEQ
    *(f4*)(hs + BATCH * 32 + b * 32 + 16 + 4 * g) = v21;

  } else {
    // ================= WAVE C : output projection =================
    unsigned WOh[4], WOl[4];
    {
      f4 u = *(const f4*)(Wout + 4 * g);
      f4 v = *(const f4*)(Wout + 16 + 4 * g);
      splitpk(u[0], u[1], WOh[0], WOl[0]);
      splitpk(u[2], u[3], WOh[1], WOl[1]);
      splitpk(v[0], v[1], WOh[2], WOl[2]);
      splitpk(v[2], v[3], WOh[3], WOl[3]);
    }
    const float bO = boutp[0];

#pragma unroll 1
    for (int m = 0; m < NSLOT; ++m) {
      if (m >= 3) {
        int p = (m - 1) & 1;
        u4v th[SLOT], tl[SLOT];
#pragma unroll
        for (int j = 0; j < SLOT; ++j) {
          th[j] = *(const u4v*)&LB2[p][j][0][li];
          tl[j] = *(const u4v*)&LB2[p][j][1][li];
        }
#pragma unroll
        for (int j = 0; j < SLOT; ++j) {
          unsigned B2h[4] = { th[j][0], th[j][1], th[j][2], th[j][3] };
          unsigned B2l[4] = { tl[j][0], tl[j][1], tl[j][2], tl[j][3] };
          f4 cO = MF(WOh, B2h, z);
          f4 cP = MF(WOh, B2l, z);
          f4 cQ = MF(WOl, B2h, z);
          int t = SLOT * (m - 3) + j;
          if (g == 0) out[t * BATCH + b] = (cO[0] + cP[0]) + (cQ[0] + bO);
        }
      }
      __syncthreads();
    }
  }
}

extern "C" void kernel_launch(void* const* d_in, const int* in_sizes, int n_in,
                              void* d_out, int out_size, void* d_ws, size_t ws_size,
                              hipStream_t stream) {
  rnn_fused<<<dim3(128), dim3(256), 0, stream>>>(
      (const float*)d_in[0],  (const float*)d_in[1],  (const float*)d_in[2],
      (const float*)d_in[3],  (const float*)d_in[4],  (const float*)d_in[5],
      (const float*)d_in[6],  (const float*)d_in[7],  (const float*)d_in[8],
      (const float*)d_in[9],  (const float*)d_in[10], (const float*)d_in[11],
      (float*)d_out);
}

// Round 9
// 212.936 us; speedup vs baseline: 1.2736x; 1.2736x over previous
//
#include <hip/hip_runtime.h>

typedef __attribute__((ext_vector_type(8))) short s8v;
typedef __attribute__((ext_vector_type(4))) float f4;
typedef __attribute__((ext_vector_type(4))) unsigned u4v;

#define SEQ 1024
#define BATCH 2048
#define SLOT 4
#define NSLOT (SEQ / SLOT + 3)   // 259

// Split (a,b) into bf16 hi-plane word and bf16 lo-plane (residual) word.
// hi word: low16 = a[31:16], high16 = b[31:16] — one v_perm_b32.
// Numerically identical to the bit-op version (verified R7: same absmax).
__device__ __forceinline__ void splitpk(float a, float b, unsigned &hw, unsigned &lw) {
  unsigned au = __float_as_uint(a), bu = __float_as_uint(b);
  hw = __builtin_amdgcn_perm(bu, au, 0x07060302u);
  float la = a - __uint_as_float(au & 0xffff0000u);
  float lb = b - __uint_as_float(bu & 0xffff0000u);
  lw = __builtin_amdgcn_perm(__float_as_uint(lb), __float_as_uint(la), 0x07060302u);
}

__device__ __forceinline__ f4 MF(const unsigned (&a)[4], const unsigned (&b)[4], f4 c) {
  union U { unsigned u[4]; s8v v; } A, B;
  A.u[0] = a[0]; A.u[1] = a[1]; A.u[2] = a[2]; A.u[3] = a[3];
  B.u[0] = b[0]; B.u[1] = b[1]; B.u[2] = b[2]; B.u[3] = b[3];
  return __builtin_amdgcn_mfma_f32_16x16x32_bf16(A.v, B.v, c, 0, 0, 0);
}

// k-map (same on A and B operands so any mismatch with the true HW map
// cancels): elem i of lane-group g -> k = 4g+i (i<4), k = 16+4g+(i-4) (i>=4).
// C-layout (row = 4g + reg) feeds the next B-fragment with NO cross-lane moves.

__device__ __forceinline__ void conv(f4 va, f4 vb, unsigned (&hi)[4], unsigned (&lo)[4]) {
  splitpk(va[0], va[1], hi[0], lo[0]);
  splitpk(va[2], va[3], hi[1], lo[1]);
  splitpk(vb[0], vb[1], hi[2], lo[2]);
  splitpk(vb[2], vb[3], hi[3], lo[3]);
}

__device__ __forceinline__ void loadA(const float* W, int row, int g,
                                      unsigned (&hi)[4], unsigned (&lo)[4]) {
  const float* p = W + row * 32;
  f4 u = *(const f4*)(p + 4 * g);
  f4 v = *(const f4*)(p + 16 + 4 * g);
  splitpk(u[0], u[1], hi[0], lo[0]);
  splitpk(u[2], u[3], hi[1], lo[1]);
  splitpk(v[0], v[1], hi[2], lo[2]);
  splitpk(v[2], v[3], hi[3], lo[3]);
}

// 4-wave feed-forward pipeline, 4 timesteps per slot, 1 barrier per slot.
//   wave 0 (A): h1 recurrence (in regs)          -> LH1[m&1]
//   wave 1 (D): P = Wih1@h1 + b1 (feed-forward)  -> LP [m&1]
//   wave 2 (B): h2 = relu(P + Whh1@h2) (in regs) -> LB2[m&1]
//   wave 3 (C): out = Wout.h2 + bO
// Skews: A slots [0,255], D [1,256], B [2,257], C [3,258].
// All MFMA plane-sums are C-CHAINED (accumulator forwarding); the only
// MFMA->VALU readouts are the two relu points (waves A and B).
__global__ __launch_bounds__(256) void rnn_fused(
    const float* __restrict__ x,    const float* __restrict__ h0,
    const float* __restrict__ Wih0, const float* __restrict__ Whh0,
    const float* __restrict__ bih0, const float* __restrict__ bhh0,
    const float* __restrict__ Wih1, const float* __restrict__ Whh1,
    const float* __restrict__ bih1, const float* __restrict__ bhh1,
    const float* __restrict__ Wout, const float* __restrict__ boutp,
    float* __restrict__ out)
{
  const int tid  = threadIdx.x;
  const int wid  = tid >> 6;
  const int lane = tid & 63;
  const int c = lane & 15;      // batch column within tile (also A-frag row)
  const int g = lane >> 4;      // lane group 0..3
  const int b = blockIdx.x * 16 + c;
  const unsigned li = (unsigned)lane * 4u;

  // All planes are b128-per-lane at lane*16B — the conflict-minimal pattern.
  __shared__ unsigned LH1[2][SLOT][2][256];  // [parity][step j][hi/lo][u32]
  __shared__ float    LP [2][SLOT][2][256];  // [parity][step j][P0/P1][f32]
  __shared__ unsigned LB2[2][SLOT][2][256];  // [parity][step j][hi/lo][u32]

  const f4 z = {0.f, 0.f, 0.f, 0.f};
  float* hs = out + SEQ * BATCH;

  if (wid == 0) {
    // ================= WAVE A : layer 0 (h1 recurrence) =================
    unsigned W00h[4], W00l[4], W01h[4], W01l[4];
    loadA(Whh0, c,      g, W00h, W00l);
    loadA(Whh0, 16 + c, g, W01h, W01l);
    f4 wih0A, wih0B, b0A, b0B;
#pragma unroll
    for (int r = 0; r < 4; ++r) {
      int j0 = 4 * g + r, j1 = 16 + 4 * g + r;
      wih0A[r] = Wih0[j0];            wih0B[r] = Wih0[j1];
      b0A[r]   = bih0[j0] + bhh0[j0]; b0B[r]   = bih0[j1] + bhh0[j1];
    }
    unsigned B1h[4], B1l[4];
    {
      const float* p1 = h0 + b * 32;
      f4 u = *(const f4*)(p1 + 4 * g);
      f4 v = *(const f4*)(p1 + 16 + 4 * g);
      splitpk(u[0], u[1], B1h[0], B1l[0]);
      splitpk(u[2], u[3], B1h[1], B1l[1]);
      splitpk(v[0], v[1], B1h[2], B1l[2]);
      splitpk(v[2], v[3], B1h[3], B1l[3]);
    }
    f4 v10 = z, v11 = z;
    float xc[SLOT];
#pragma unroll
    for (int j = 0; j < SLOT; ++j) xc[j] = x[j * BATCH + b];

#pragma unroll 1
    for (int m = 0; m < NSLOT; ++m) {
      if (m < SEQ / SLOT) {
        float xn[SLOT];
#pragma unroll
        for (int j = 0; j < SLOT; ++j) {
          int ti = SLOT * m + SLOT + j;
          xn[j] = x[(ti < SEQ ? ti : SEQ - 1) * BATCH + b];
        }
#pragma unroll
        for (int j = 0; j < SLOT; ++j) {
          float XV = xc[j];
          f4 c00, c01;
#pragma unroll
          for (int r = 0; r < 4; ++r) {
            c00[r] = fmaf(XV, wih0A[r], b0A[r]);
            c01[r] = fmaf(XV, wih0B[r], b0B[r]);
          }
          // fully C-chained plane sum (accumulator forwarding)
          c00 = MF(W00h, B1h, c00);  c01 = MF(W01h, B1h, c01);
          c00 = MF(W00h, B1l, c00);  c01 = MF(W01h, B1l, c01);
          c00 = MF(W00l, B1h, c00);  c01 = MF(W01l, B1h, c01);
#pragma unroll
          for (int r = 0; r < 4; ++r) {
            v10[r] = fmaxf(c00[r], 0.f);
            v11[r] = fmaxf(c01[r], 0.f);
          }
          conv(v10, v11, B1h, B1l);
          u4v wh = { B1h[0], B1h[1], B1h[2], B1h[3] };
          u4v wl = { B1l[0], B1l[1], B1l[2], B1l[3] };
          *(u4v*)&LH1[m & 1][j][0][li] = wh;
          *(u4v*)&LH1[m & 1][j][1][li] = wl;
        }
#pragma unroll
        for (int j = 0; j < SLOT; ++j) xc[j] = xn[j];
      }
      __syncthreads();
    }
    *(f4*)(hs + b * 32 + 4 * g)      = v10;   // h1_SEQ
    *(f4*)(hs + b * 32 + 16 + 4 * g) = v11;

  } else if (wid == 1) {
    // ========== WAVE D : feeder P = Wih1 @ h1 + b1 (full 32 rows) ==========
    // Fully chained; accumulator written STRAIGHT to LDS (no VALU readout).
    unsigned WiH0[4], WiL0[4], WiH1[4], WiL1[4];
    loadA(Wih1, c,      g, WiH0, WiL0);
    loadA(Wih1, 16 + c, g, WiH1, WiL1);
    f4 b1A, b1B;
#pragma unroll
    for (int r = 0; r < 4; ++r) {
      int j0 = 4 * g + r, j1 = 16 + 4 * g + r;
      b1A[r] = bih1[j0] + bhh1[j0];
      b1B[r] = bih1[j1] + bhh1[j1];
    }

#pragma unroll 1
    for (int m = 0; m < NSLOT; ++m) {
      if (m >= 1 && m <= SEQ / SLOT) {
        int p = (m - 1) & 1;
        u4v fh[SLOT], fl[SLOT];
#pragma unroll
        for (int j = 0; j < SLOT; ++j) {
          fh[j] = *(const u4v*)&LH1[p][j][0][li];
          fl[j] = *(const u4v*)&LH1[p][j][1][li];
        }
#pragma unroll
        for (int j = 0; j < SLOT; ++j) {
          unsigned B1h[4] = { fh[j][0], fh[j][1], fh[j][2], fh[j][3] };
          unsigned B1l[4] = { fl[j][0], fl[j][1], fl[j][2], fl[j][3] };
          f4 P0 = MF(WiH0, B1h, b1A);
          P0 = MF(WiH0, B1l, P0);
          P0 = MF(WiL0, B1h, P0);
          f4 P1 = MF(WiH1, B1h, b1B);
          P1 = MF(WiH1, B1l, P1);
          P1 = MF(WiL1, B1h, P1);
          *(f4*)&LP[m & 1][j][0][li] = P0;
          *(f4*)&LP[m & 1][j][1][li] = P1;
        }
      }
      __syncthreads();
    }

  } else if (wid == 2) {
    // ========== WAVE B : h2 recurrence = relu(P + Whh1 @ h2) ==========
    // Chained with C-in = P; single relu readout per row-half.
    unsigned WhH0[4], WhL0[4], WhH1[4], WhL1[4];
    loadA(Whh1, c,      g, WhH0, WhL0);
    loadA(Whh1, 16 + c, g, WhH1, WhL1);
    unsigned B2h[4], B2l[4];
    f4 v20 = z, v21 = z;
    {
      const float* p2 = h0 + BATCH * 32 + b * 32;
      f4 u = *(const f4*)(p2 + 4 * g);
      f4 v = *(const f4*)(p2 + 16 + 4 * g);
      splitpk(u[0], u[1], B2h[0], B2l[0]);
      splitpk(u[2], u[3], B2h[1], B2l[1]);
      splitpk(v[0], v[1], B2h[2], B2l[2]);
      splitpk(v[2], v[3], B2h[3], B2l[3]);
      v20 = u; v21 = v;
    }

#pragma unroll 1
    for (int m = 0; m < NSLOT; ++m) {
      if (m >= 2 && m <= SEQ / SLOT + 1) {
        int p = (m - 1) & 1;
        f4 Pa[SLOT], Pb[SLOT];
#pragma unroll
        for (int j = 0; j < SLOT; ++j) {
          Pa[j] = *(const f4*)&LP[p][j][0][li];
          Pb[j] = *(const f4*)&LP[p][j][1][li];
        }
#pragma unroll
        for (int j = 0; j < SLOT; ++j) {
          f4 r0 = MF(WhH0, B2h, Pa[j]);
          r0 = MF(WhH0, B2l, r0);
          r0 = MF(WhL0, B2h, r0);
          f4 s0 = MF(WhH1, B2h, Pb[j]);
          s0 = MF(WhH1, B2l, s0);
          s0 = MF(WhL1, B2h, s0);
#pragma unroll
          for (int r = 0; r < 4; ++r) {
            v20[r] = fmaxf(r0[r], 0.f);
            v21[r] = fmaxf(s0[r], 0.f);
          }
          conv(v20, v21, B2h, B2l);
          u4v wh = { B2h[0], B2h[1], B2h[2], B2h[3] };
          u4v wl = { B2l[0], B2l[1], B2l[2], B2l[3] };
          *(u4v*)&LB2[m & 1][j][0][li] = wh;
          *(u4v*)&LB2[m & 1][j][1][li] = wl;
        }
      }
      __syncthreads();
    }
    *(f4*)(hs + BATCH * 32 + b * 32 + 4 * g)      = v20;  // h2_SEQ
    *(f4*)(hs + BATCH * 32 + b * 32 + 16 + 4 * g) = v21;

  } else {
    // ================= WAVE C : output projection =================
    // Chained with bias folded into C-in; store accumulator directly.
    unsigned WOh[4], WOl[4];
    {
      f4 u = *(const f4*)(Wout + 4 * g);
      f4 v = *(const f4*)(Wout + 16 + 4 * g);
      splitpk(u[0], u[1], WOh[0], WOl[0]);
      splitpk(u[2], u[3], WOh[1], WOl[1]);
      splitpk(v[0], v[1], WOh[2], WOl[2]);
      splitpk(v[2], v[3], WOh[3], WOl[3]);
    }
    const float bO = boutp[0];
    const f4 cb = { bO, bO, bO, bO };

#pragma unroll 1
    for (int m = 0; m < NSLOT; ++m) {
      if (m >= 3) {
        int p = (m - 1) & 1;
        u4v th[SLOT], tl[SLOT];
#pragma unroll
        for (int j = 0; j < SLOT; ++j) {
          th[j] = *(const u4v*)&LB2[p][j][0][li];
          tl[j] = *(const u4v*)&LB2[p][j][1][li];
        }
#pragma unroll
        for (int j = 0; j < SLOT; ++j) {
          unsigned B2h[4] = { th[j][0], th[j][1], th[j][2], th[j][3] };
          unsigned B2l[4] = { tl[j][0], tl[j][1], tl[j][2], tl[j][3] };
          f4 cO = MF(WOh, B2h, cb);
          cO = MF(WOh, B2l, cO);
          cO = MF(WOl, B2h, cO);
          int t = SLOT * (m - 3) + j;
          if (g == 0) out[t * BATCH + b] = cO[0];
        }
      }
      __syncthreads();
    }
  }
}

extern "C" void kernel_launch(void* const* d_in, const int* in_sizes, int n_in,
                              void* d_out, int out_size, void* d_ws, size_t ws_size,
                              hipStream_t stream) {
  rnn_fused<<<dim3(128), dim3(256), 0, stream>>>(
      (const float*)d_in[0],  (const float*)d_in[1],  (const float*)d_in[2],
      (const float*)d_in[3],  (const float*)d_in[4],  (const float*)d_in[5],
      (const float*)d_in[6],  (const float*)d_in[7],  (const float*)d_in[8],
      (const float*)d_in[9],  (const float*)d_in[10], (const float*)d_in[11],
      (float*)d_out);
}

// Round 10
// 189.102 us; speedup vs baseline: 1.4341x; 1.1260x over previous
//
#include <hip/hip_runtime.h>

typedef __attribute__((ext_vector_type(8))) short s8v;
typedef __attribute__((ext_vector_type(4))) float f4;
typedef __attribute__((ext_vector_type(4))) unsigned u4v;

#define SEQ 1024
#define BATCH 2048
#define SLOT 4
#define NSLOT (SEQ / SLOT + 3)   // 259

// Split (a,b) into bf16 hi-plane word and bf16 lo-plane (residual) word.
// hi word: low16 = a[31:16], high16 = b[31:16] — one v_perm_b32.
__device__ __forceinline__ void splitpk(float a, float b, unsigned &hw, unsigned &lw) {
  unsigned au = __float_as_uint(a), bu = __float_as_uint(b);
  hw = __builtin_amdgcn_perm(bu, au, 0x07060302u);
  float la = a - __uint_as_float(au & 0xffff0000u);
  float lb = b - __uint_as_float(bu & 0xffff0000u);
  lw = __builtin_amdgcn_perm(__float_as_uint(lb), __float_as_uint(la), 0x07060302u);
}

__device__ __forceinline__ f4 MF(const unsigned (&a)[4], const unsigned (&b)[4], f4 c) {
  union U { unsigned u[4]; s8v v; } A, B;
  A.u[0] = a[0]; A.u[1] = a[1]; A.u[2] = a[2]; A.u[3] = a[3];
  B.u[0] = b[0]; B.u[1] = b[1]; B.u[2] = b[2]; B.u[3] = b[3];
  return __builtin_amdgcn_mfma_f32_16x16x32_bf16(A.v, B.v, c, 0, 0, 0);
}

// k-map (same on A and B operands so any mismatch with the true HW map
// cancels): elem i of lane-group g -> k = 4g+i (i<4), k = 16+4g+(i-4) (i>=4).
// C-layout (row = 4g + reg) feeds the next B-fragment with NO cross-lane moves.

__device__ __forceinline__ void conv(f4 va, f4 vb, unsigned (&hi)[4], unsigned (&lo)[4]) {
  splitpk(va[0], va[1], hi[0], lo[0]);
  splitpk(va[2], va[3], hi[1], lo[1]);
  splitpk(vb[0], vb[1], hi[2], lo[2]);
  splitpk(vb[2], vb[3], hi[3], lo[3]);
}

__device__ __forceinline__ void loadA(const float* W, int row, int g,
                                      unsigned (&hi)[4], unsigned (&lo)[4]) {
  const float* p = W + row * 32;
  f4 u = *(const f4*)(p + 4 * g);
  f4 v = *(const f4*)(p + 16 + 4 * g);
  splitpk(u[0], u[1], hi[0], lo[0]);
  splitpk(u[2], u[3], hi[1], lo[1]);
  splitpk(v[0], v[1], hi[2], lo[2]);
  splitpk(v[2], v[3], hi[3], lo[3]);
}

// 4-wave feed-forward pipeline, 4 timesteps per slot, 1 barrier per slot.
//   wave 0 (A): h1 recurrence (in regs)          -> LH1[m&1]   [2-plane W]
//   wave 1 (D): P = Wih1@h1 + b1 (feed-forward)  -> LP [m&1]   [3-plane]
//   wave 2 (B): h2 = relu(P + Whh1@h2) (in regs) -> LB2[m&1]   [2-plane W]
//   wave 3 (C): out = Wout.h2 + bO                             [3-plane]
// Recurrent weights (Whh0, Whh1) are single-plane bf16; hidden states stay
// hi+lo split; Wih1/Wout keep the full 3-plane product. Binding waves (A,B)
// drop 6 -> 4 MFMAs.
__global__ __launch_bounds__(256) void rnn_fused(
    const float* __restrict__ x,    const float* __restrict__ h0,
    const float* __restrict__ Wih0, const float* __restrict__ Whh0,
    const float* __restrict__ bih0, const float* __restrict__ bhh0,
    const float* __restrict__ Wih1, const float* __restrict__ Whh1,
    const float* __restrict__ bih1, const float* __restrict__ bhh1,
    const float* __restrict__ Wout, const float* __restrict__ boutp,
    float* __restrict__ out)
{
  const int tid  = threadIdx.x;
  const int wid  = tid >> 6;
  const int lane = tid & 63;
  const int c = lane & 15;      // batch column within tile (also A-frag row)
  const int g = lane >> 4;      // lane group 0..3
  const int b = blockIdx.x * 16 + c;
  const unsigned li = (unsigned)lane * 4u;

  // All planes are b128-per-lane at lane*16B — the conflict-minimal pattern.
  __shared__ unsigned LH1[2][SLOT][2][256];  // [parity][step j][hi/lo][u32]
  __shared__ float    LP [2][SLOT][2][256];  // [parity][step j][P0/P1][f32]
  __shared__ unsigned LB2[2][SLOT][2][256];  // [parity][step j][hi/lo][u32]

  const f4 z = {0.f, 0.f, 0.f, 0.f};
  float* hs = out + SEQ * BATCH;

  if (wid == 0) {
    // ================= WAVE A : layer 0 (h1 recurrence) =================
    unsigned W00h[4], W00l[4], W01h[4], W01l[4];
    loadA(Whh0, c,      g, W00h, W00l);   // lo planes unused (2-plane scheme)
    loadA(Whh0, 16 + c, g, W01h, W01l);
    f4 wih0A, wih0B, b0A, b0B;
#pragma unroll
    for (int r = 0; r < 4; ++r) {
      int j0 = 4 * g + r, j1 = 16 + 4 * g + r;
      wih0A[r] = Wih0[j0];            wih0B[r] = Wih0[j1];
      b0A[r]   = bih0[j0] + bhh0[j0]; b0B[r]   = bih0[j1] + bhh0[j1];
    }
    unsigned B1h[4], B1l[4];
    {
      const float* p1 = h0 + b * 32;
      f4 u = *(const f4*)(p1 + 4 * g);
      f4 v = *(const f4*)(p1 + 16 + 4 * g);
      splitpk(u[0], u[1], B1h[0], B1l[0]);
      splitpk(u[2], u[3], B1h[1], B1l[1]);
      splitpk(v[0], v[1], B1h[2], B1l[2]);
      splitpk(v[2], v[3], B1h[3], B1l[3]);
    }
    f4 v10 = z, v11 = z;
    float xc[SLOT];
#pragma unroll
    for (int j = 0; j < SLOT; ++j) xc[j] = x[j * BATCH + b];

#pragma unroll 1
    for (int m = 0; m < NSLOT; ++m) {
      if (m < SEQ / SLOT) {
        float xn[SLOT];
#pragma unroll
        for (int j = 0; j < SLOT; ++j) {
          int ti = SLOT * m + SLOT + j;
          xn[j] = x[(ti < SEQ ? ti : SEQ - 1) * BATCH + b];
        }
#pragma unroll
        for (int j = 0; j < SLOT; ++j) {
          float XV = xc[j];
          f4 c00, c01;
#pragma unroll
          for (int r = 0; r < 4; ++r) {
            c00[r] = fmaf(XV, wih0A[r], b0A[r]);
            c01[r] = fmaf(XV, wih0B[r], b0B[r]);
          }
          // 2-plane: W_hi (bf16) x (h_hi + h_lo), C-chained.
          c00 = MF(W00h, B1h, c00);  c01 = MF(W01h, B1h, c01);
          c00 = MF(W00h, B1l, c00);  c01 = MF(W01h, B1l, c01);
#pragma unroll
          for (int r = 0; r < 4; ++r) {
            v10[r] = fmaxf(c00[r], 0.f);
            v11[r] = fmaxf(c01[r], 0.f);
          }
          conv(v10, v11, B1h, B1l);
          u4v wh = { B1h[0], B1h[1], B1h[2], B1h[3] };
          u4v wl = { B1l[0], B1l[1], B1l[2], B1l[3] };
          *(u4v*)&LH1[m & 1][j][0][li] = wh;
          *(u4v*)&LH1[m & 1][j][1][li] = wl;
        }
#pragma unroll
        for (int j = 0; j < SLOT; ++j) xc[j] = xn[j];
      }
      __syncthreads();
    }
    *(f4*)(hs + b * 32 + 4 * g)      = v10;   // h1_SEQ
    *(f4*)(hs + b * 32 + 16 + 4 * g) = v11;

  } else if (wid == 1) {
    // ========== WAVE D : feeder P = Wih1 @ h1 + b1 (full 3-plane) ==========
    unsigned WiH0[4], WiL0[4], WiH1[4], WiL1[4];
    loadA(Wih1, c,      g, WiH0, WiL0);
    loadA(Wih1, 16 + c, g, WiH1, WiL1);
    f4 b1A, b1B;
#pragma unroll
    for (int r = 0; r < 4; ++r) {
      int j0 = 4 * g + r, j1 = 16 + 4 * g + r;
      b1A[r] = bih1[j0] + bhh1[j0];
      b1B[r] = bih1[j1] + bhh1[j1];
    }

#pragma unroll 1
    for (int m = 0; m < NSLOT; ++m) {
      if (m >= 1 && m <= SEQ / SLOT) {
        int p = (m - 1) & 1;
        u4v fh[SLOT], fl[SLOT];
#pragma unroll
        for (int j = 0; j < SLOT; ++j) {
          fh[j] = *(const u4v*)&LH1[p][j][0][li];
          fl[j] = *(const u4v*)&LH1[p][j][1][li];
        }
#pragma unroll
        for (int j = 0; j < SLOT; ++j) {
          unsigned B1h[4] = { fh[j][0], fh[j][1], fh[j][2], fh[j][3] };
          unsigned B1l[4] = { fl[j][0], fl[j][1], fl[j][2], fl[j][3] };
          f4 P0 = MF(WiH0, B1h, b1A);
          P0 = MF(WiH0, B1l, P0);
          P0 = MF(WiL0, B1h, P0);
          f4 P1 = MF(WiH1, B1h, b1B);
          P1 = MF(WiH1, B1l, P1);
          P1 = MF(WiL1, B1h, P1);
          *(f4*)&LP[m & 1][j][0][li] = P0;
          *(f4*)&LP[m & 1][j][1][li] = P1;
        }
      }
      __syncthreads();
    }

  } else if (wid == 2) {
    // ========== WAVE B : h2 recurrence = relu(P + Whh1 @ h2), 2-plane ==========
    unsigned WhH0[4], WhL0[4], WhH1[4], WhL1[4];
    loadA(Whh1, c,      g, WhH0, WhL0);   // lo planes unused
    loadA(Whh1, 16 + c, g, WhH1, WhL1);
    unsigned B2h[4], B2l[4];
    f4 v20 = z, v21 = z;
    {
      const float* p2 = h0 + BATCH * 32 + b * 32;
      f4 u = *(const f4*)(p2 + 4 * g);
      f4 v = *(const f4*)(p2 + 16 + 4 * g);
      splitpk(u[0], u[1], B2h[0], B2l[0]);
      splitpk(u[2], u[3], B2h[1], B2l[1]);
      splitpk(v[0], v[1], B2h[2], B2l[2]);
      splitpk(v[2], v[3], B2h[3], B2l[3]);
      v20 = u; v21 = v;
    }

#pragma unroll 1
    for (int m = 0; m < NSLOT; ++m) {
      if (m >= 2 && m <= SEQ / SLOT + 1) {
        int p = (m - 1) & 1;
        f4 Pa[SLOT], Pb[SLOT];
#pragma unroll
        for (int j = 0; j < SLOT; ++j) {
          Pa[j] = *(const f4*)&LP[p][j][0][li];
          Pb[j] = *(const f4*)&LP[p][j][1][li];
        }
#pragma unroll
        for (int j = 0; j < SLOT; ++j) {
          f4 r0 = MF(WhH0, B2h, Pa[j]);
          r0 = MF(WhH0, B2l, r0);
          f4 s0 = MF(WhH1, B2h, Pb[j]);
          s0 = MF(WhH1, B2l, s0);
#pragma unroll
          for (int r = 0; r < 4; ++r) {
            v20[r] = fmaxf(r0[r], 0.f);
            v21[r] = fmaxf(s0[r], 0.f);
          }
          conv(v20, v21, B2h, B2l);
          u4v wh = { B2h[0], B2h[1], B2h[2], B2h[3] };
          u4v wl = { B2l[0], B2l[1], B2l[2], B2l[3] };
          *(u4v*)&LB2[m & 1][j][0][li] = wh;
          *(u4v*)&LB2[m & 1][j][1][li] = wl;
        }
      }
      __syncthreads();
    }
    *(f4*)(hs + BATCH * 32 + b * 32 + 4 * g)      = v20;  // h2_SEQ
    *(f4*)(hs + BATCH * 32 + b * 32 + 16 + 4 * g) = v21;

  } else {
    // ================= WAVE C : output projection (3-plane) =================
    unsigned WOh[4], WOl[4];
    {
      f4 u = *(const f4*)(Wout + 4 * g);
      f4 v = *(const f4*)(Wout + 16 + 4 * g);
      splitpk(u[0], u[1], WOh[0], WOl[0]);
      splitpk(u[2], u[3], WOh[1], WOl[1]);
      splitpk(v[0], v[1], WOh[2], WOl[2]);
      splitpk(v[2], v[3], WOh[3], WOl[3]);
    }
    const float bO = boutp[0];
    const f4 cb = { bO, bO, bO, bO };

#pragma unroll 1
    for (int m = 0; m < NSLOT; ++m) {
      if (m >= 3) {
        int p = (m - 1) & 1;
        u4v th[SLOT], tl[SLOT];
#pragma unroll
        for (int j = 0; j < SLOT; ++j) {
          th[j] = *(const u4v*)&LB2[p][j][0][li];
          tl[j] = *(const u4v*)&LB2[p][j][1][li];
        }
#pragma unroll
        for (int j = 0; j < SLOT; ++j) {
          unsigned B2h[4] = { th[j][0], th[j][1], th[j][2], th[j][3] };
          unsigned B2l[4] = { tl[j][0], tl[j][1], tl[j][2], tl[j][3] };
          f4 cO = MF(WOh, B2h, cb);
          cO = MF(WOh, B2l, cO);
          cO = MF(WOl, B2h, cO);
          int t = SLOT * (m - 3) + j;
          if (g == 0) out[t * BATCH + b] = cO[0];
        }
      }
      __syncthreads();
    }
  }
}

extern "C" void kernel_launch(void* const* d_in, const int* in_sizes, int n_in,
                              void* d_out, int out_size, void* d_ws, size_t ws_size,
                              hipStream_t stream) {
  rnn_fused<<<dim3(128), dim3(256), 0, stream>>>(
      (const float*)d_in[0],  (const float*)d_in[1],  (const float*)d_in[2],
      (const float*)d_in[3],  (const float*)d_in[4],  (const float*)d_in[5],
      (const float*)d_in[6],  (const float*)d_in[7],  (const float*)d_in[8],
      (const float*)d_in[9],  (const float*)d_in[10], (const float*)d_in[11],
      (float*)d_out);
}

// Round 11
// 143.097 us; speedup vs baseline: 1.8952x; 1.3215x over previous
//
#include <hip/hip_runtime.h>

typedef __attribute__((ext_vector_type(8))) short s8v;
typedef __attribute__((ext_vector_type(4))) float f4;
typedef __attribute__((ext_vector_type(4))) unsigned u4v;

#define SEQ 1024
#define BATCH 2048
#define SLOT 4
#define NSLOT (SEQ / SLOT + 3)   // 259

// RNE-pack two f32 into one u32 of 2 bf16 via v_cvt_pk_bf16_f32.
// Operand-order ambiguity is harmless: this SAME packer builds every
// A-fragment and every B-fragment, so a within-pair swap applies the same
// k-permutation to both MFMA operands and cancels in the dot product.
__device__ __forceinline__ unsigned pack2(float a, float b) {
  unsigned r;
  asm("v_cvt_pk_bf16_f32 %0, %1, %2" : "=v"(r) : "v"(a), "v"(b));
  return r;
}

__device__ __forceinline__ f4 MF(const unsigned (&a)[4], const unsigned (&b)[4], f4 c) {
  union U { unsigned u[4]; s8v v; } A, B;
  A.u[0] = a[0]; A.u[1] = a[1]; A.u[2] = a[2]; A.u[3] = a[3];
  B.u[0] = b[0]; B.u[1] = b[1]; B.u[2] = b[2]; B.u[3] = b[3];
  return __builtin_amdgcn_mfma_f32_16x16x32_bf16(A.v, B.v, c, 0, 0, 0);
}

// k-map (same on A and B operands so any mismatch with the true HW map
// cancels): elem i of lane-group g -> k = 4g+i (i<4), k = 16+4g+(i-4) (i>=4).
// C-layout (row = 4g + reg) feeds the next B-fragment with NO cross-lane moves.

// C-regs (va = rows 4g+r, vb = rows 16+4g+r) -> single-plane bf16 B-fragment.
__device__ __forceinline__ void convh(f4 va, f4 vb, unsigned (&hi)[4]) {
  hi[0] = pack2(va[0], va[1]);
  hi[1] = pack2(va[2], va[3]);
  hi[2] = pack2(vb[0], vb[1]);
  hi[3] = pack2(vb[2], vb[3]);
}

// Load a single-plane bf16 A fragment (row fixed per lane).
__device__ __forceinline__ void loadAh(const float* W, int row, int g, unsigned (&hi)[4]) {
  const float* p = W + row * 32;
  f4 u = *(const f4*)(p + 4 * g);
  f4 v = *(const f4*)(p + 16 + 4 * g);
  hi[0] = pack2(u[0], u[1]);
  hi[1] = pack2(u[2], u[3]);
  hi[2] = pack2(v[0], v[1]);
  hi[3] = pack2(v[2], v[3]);
}

// 4-wave feed-forward pipeline, 4 timesteps per slot, 1 barrier per slot.
//   wave 0 (A): h1 recurrence (in regs)          -> LH1[m&1]   [2 MFMA]
//   wave 1 (D): P = Wih1@h1 + b1 (feed-forward)  -> LP [m&1]   [2 MFMA]
//   wave 2 (B): h2 = relu(P + Whh1@h2) (in regs) -> LB2[m&1]   [2 MFMA]
//   wave 3 (C): out = Wout.h2 + bO                             [1 MFMA]
// All operands plain bf16 (RNE); biases/x/relu stay f32.
// Skews: A slots [0,255], D [1,256], B [2,257], C [3,258].
__global__ __launch_bounds__(256) void rnn_fused(
    const float* __restrict__ x,    const float* __restrict__ h0,
    const float* __restrict__ Wih0, const float* __restrict__ Whh0,
    const float* __restrict__ bih0, const float* __restrict__ bhh0,
    const float* __restrict__ Wih1, const float* __restrict__ Whh1,
    const float* __restrict__ bih1, const float* __restrict__ bhh1,
    const float* __restrict__ Wout, const float* __restrict__ boutp,
    float* __restrict__ out)
{
  const int tid  = threadIdx.x;
  const int wid  = tid >> 6;
  const int lane = tid & 63;
  const int c = lane & 15;      // batch column within tile (also A-frag row)
  const int g = lane >> 4;      // lane group 0..3
  const int b = blockIdx.x * 16 + c;
  const unsigned li = (unsigned)lane * 4u;

  // b128-per-lane at lane*16B — conflict-free pattern (verified R6+).
  __shared__ unsigned LH1[2][SLOT][256];     // [parity][step j][u32]
  __shared__ float    LP [2][SLOT][2][256];  // [parity][step j][P0/P1][f32]
  __shared__ unsigned LB2[2][SLOT][256];     // [parity][step j][u32]

  const f4 z = {0.f, 0.f, 0.f, 0.f};
  float* hs = out + SEQ * BATCH;

  if (wid == 0) {
    // ================= WAVE A : layer 0 (h1 recurrence) =================
    unsigned W00h[4], W01h[4];
    loadAh(Whh0, c,      g, W00h);
    loadAh(Whh0, 16 + c, g, W01h);
    f4 wih0A, wih0B, b0A, b0B;
#pragma unroll
    for (int r = 0; r < 4; ++r) {
      int j0 = 4 * g + r, j1 = 16 + 4 * g + r;
      wih0A[r] = Wih0[j0];            wih0B[r] = Wih0[j1];
      b0A[r]   = bih0[j0] + bhh0[j0]; b0B[r]   = bih0[j1] + bhh0[j1];
    }
    unsigned B1h[4];
    {
      const float* p1 = h0 + b * 32;
      f4 u = *(const f4*)(p1 + 4 * g);
      f4 v = *(const f4*)(p1 + 16 + 4 * g);
      convh(u, v, B1h);
    }
    f4 v10 = z, v11 = z;
    float xc[SLOT];
#pragma unroll
    for (int j = 0; j < SLOT; ++j) xc[j] = x[j * BATCH + b];

#pragma unroll 1
    for (int m = 0; m < NSLOT; ++m) {
      if (m < SEQ / SLOT) {
        float xn[SLOT];
#pragma unroll
        for (int j = 0; j < SLOT; ++j) {
          int ti = SLOT * m + SLOT + j;
          xn[j] = x[(ti < SEQ ? ti : SEQ - 1) * BATCH + b];
        }
#pragma unroll
        for (int j = 0; j < SLOT; ++j) {
          float XV = xc[j];
          f4 c00, c01;
#pragma unroll
          for (int r = 0; r < 4; ++r) {
            c00[r] = fmaf(XV, wih0A[r], b0A[r]);
            c01[r] = fmaf(XV, wih0B[r], b0B[r]);
          }
          c00 = MF(W00h, B1h, c00);
          c01 = MF(W01h, B1h, c01);
#pragma unroll
          for (int r = 0; r < 4; ++r) {
            v10[r] = fmaxf(c00[r], 0.f);
            v11[r] = fmaxf(c01[r], 0.f);
          }
          convh(v10, v11, B1h);
          u4v wh = { B1h[0], B1h[1], B1h[2], B1h[3] };
          *(u4v*)&LH1[m & 1][j][li] = wh;
        }
#pragma unroll
        for (int j = 0; j < SLOT; ++j) xc[j] = xn[j];
      }
      __syncthreads();
    }
    *(f4*)(hs + b * 32 + 4 * g)      = v10;   // h1_SEQ
    *(f4*)(hs + b * 32 + 16 + 4 * g) = v11;

  } else if (wid == 1) {
    // ========== WAVE D : feeder P = Wih1 @ h1 + b1 ==========
    unsigned WiH0[4], WiH1[4];
    loadAh(Wih1, c,      g, WiH0);
    loadAh(Wih1, 16 + c, g, WiH1);
    f4 b1A, b1B;
#pragma unroll
    for (int r = 0; r < 4; ++r) {
      int j0 = 4 * g + r, j1 = 16 + 4 * g + r;
      b1A[r] = bih1[j0] + bhh1[j0];
      b1B[r] = bih1[j1] + bhh1[j1];
    }

#pragma unroll 1
    for (int m = 0; m < NSLOT; ++m) {
      if (m >= 1 && m <= SEQ / SLOT) {
        int p = (m - 1) & 1;
        u4v fh[SLOT];
#pragma unroll
        for (int j = 0; j < SLOT; ++j)
          fh[j] = *(const u4v*)&LH1[p][j][li];
#pragma unroll
        for (int j = 0; j < SLOT; ++j) {
          unsigned B1h[4] = { fh[j][0], fh[j][1], fh[j][2], fh[j][3] };
          f4 P0 = MF(WiH0, B1h, b1A);
          f4 P1 = MF(WiH1, B1h, b1B);
          *(f4*)&LP[m & 1][j][0][li] = P0;
          *(f4*)&LP[m & 1][j][1][li] = P1;
        }
      }
      __syncthreads();
    }

  } else if (wid == 2) {
    // ========== WAVE B : h2 recurrence = relu(P + Whh1 @ h2) ==========
    unsigned WhH0[4], WhH1[4];
    loadAh(Whh1, c,      g, WhH0);
    loadAh(Whh1, 16 + c, g, WhH1);
    unsigned B2h[4];
    f4 v20 = z, v21 = z;
    {
      const float* p2 = h0 + BATCH * 32 + b * 32;
      f4 u = *(const f4*)(p2 + 4 * g);
      f4 v = *(const f4*)(p2 + 16 + 4 * g);
      convh(u, v, B2h);
      v20 = u; v21 = v;
    }

#pragma unroll 1
    for (int m = 0; m < NSLOT; ++m) {
      if (m >= 2 && m <= SEQ / SLOT + 1) {
        int p = (m - 1) & 1;
        f4 Pa[SLOT], Pb[SLOT];
#pragma unroll
        for (int j = 0; j < SLOT; ++j) {
          Pa[j] = *(const f4*)&LP[p][j][0][li];
          Pb[j] = *(const f4*)&LP[p][j][1][li];
        }
#pragma unroll
        for (int j = 0; j < SLOT; ++j) {
          f4 r0 = MF(WhH0, B2h, Pa[j]);
          f4 s0 = MF(WhH1, B2h, Pb[j]);
#pragma unroll
          for (int r = 0; r < 4; ++r) {
            v20[r] = fmaxf(r0[r], 0.f);
            v21[r] = fmaxf(s0[r], 0.f);
          }
          convh(v20, v21, B2h);
          u4v wh = { B2h[0], B2h[1], B2h[2], B2h[3] };
          *(u4v*)&LB2[m & 1][j][li] = wh;
        }
      }
      __syncthreads();
    }
    *(f4*)(hs + BATCH * 32 + b * 32 + 4 * g)      = v20;  // h2_SEQ
    *(f4*)(hs + BATCH * 32 + b * 32 + 16 + 4 * g) = v21;

  } else {
    // ================= WAVE C : output projection =================
    unsigned WOh[4];
    {
      f4 u = *(const f4*)(Wout + 4 * g);
      f4 v = *(const f4*)(Wout + 16 + 4 * g);
      convh(u, v, WOh);
    }
    const float bO = boutp[0];
    const f4 cb = { bO, bO, bO, bO };

#pragma unroll 1
    for (int m = 0; m < NSLOT; ++m) {
      if (m >= 3) {
        int p = (m - 1) & 1;
        u4v th[SLOT];
#pragma unroll
        for (int j = 0; j < SLOT; ++j)
          th[j] = *(const u4v*)&LB2[p][j][li];
#pragma unroll
        for (int j = 0; j < SLOT; ++j) {
          unsigned B2h[4] = { th[j][0], th[j][1], th[j][2], th[j][3] };
          f4 cO = MF(WOh, B2h, cb);
          int t = SLOT * (m - 3) + j;
          if (g == 0) out[t * BATCH + b] = cO[0];
        }
      }
      __syncthreads();
    }
  }
}

extern "C" void kernel_launch(void* const* d_in, const int* in_sizes, int n_in,
                              void* d_out, int out_size, void* d_ws, size_t ws_size,
                              hipStream_t stream) {
  rnn_fused<<<dim3(128), dim3(256), 0, stream>>>(
      (const float*)d_in[0],  (const float*)d_in[1],  (const float*)d_in[2],
      (const float*)d_in[3],  (const float*)d_in[4],  (const float*)d_in[5],
      (const float*)d_in[6],  (const float*)d_in[7],  (const float*)d_in[8],
      (const float*)d_in[9],  (const float*)d_in[10], (const float*)d_in[11],
      (float*)d_out);
}

// Round 12
// 131.326 us; speedup vs baseline: 2.0651x; 1.0896x over previous
//
#include <hip/hip_runtime.h>

typedef __attribute__((ext_vector_type(8))) short s8v;
typedef __attribute__((ext_vector_type(4))) float f4;
typedef __attribute__((ext_vector_type(4))) unsigned u4v;

#define SEQ 1024
#define BATCH 2048
#define SLOT 8
#define NSLOT (SEQ / SLOT + 3)   // 131

// RNE-pack two f32 into one u32 of 2 bf16 via v_cvt_pk_bf16_f32.
// Used ONLY for MFMA A/B fragments: the same packer builds both operands, so
// any within-pair order ambiguity applies the same k-permutation to A and B
// and cancels in the dot product (sigma-invariance).
__device__ __forceinline__ unsigned pack2(float a, float b) {
  unsigned r;
  asm("v_cvt_pk_bf16_f32 %0, %1, %2" : "=v"(r) : "v"(a), "v"(b));
  return r;
}

// DETERMINISTIC pack for LDS value storage (explicit unpack on the consumer
// side, so no sigma protection): low16 = bf16(a), high16 = bf16(b), with
// +0x8000 round-half-up. Verified layout (R7): perm selector 0x07060302.
__device__ __forceinline__ unsigned permpack(float a, float b) {
  unsigned au = __float_as_uint(a) + 0x8000u;
  unsigned bu = __float_as_uint(b) + 0x8000u;
  return __builtin_amdgcn_perm(bu, au, 0x07060302u);
}

__device__ __forceinline__ f4 MF(const unsigned (&a)[4], const unsigned (&b)[4], f4 c) {
  union U { unsigned u[4]; s8v v; } A, B;
  A.u[0] = a[0]; A.u[1] = a[1]; A.u[2] = a[2]; A.u[3] = a[3];
  B.u[0] = b[0]; B.u[1] = b[1]; B.u[2] = b[2]; B.u[3] = b[3];
  return __builtin_amdgcn_mfma_f32_16x16x32_bf16(A.v, B.v, c, 0, 0, 0);
}

// k-map (same on A and B operands so any mismatch with the true HW map
// cancels): elem i of lane-group g -> k = 4g+i (i<4), k = 16+4g+(i-4) (i>=4).
// C-layout (row = 4g + reg) feeds the next B-fragment with NO cross-lane moves.

// C-regs (va = rows 4g+r, vb = rows 16+4g+r) -> single-plane bf16 B-fragment.
__device__ __forceinline__ void convh(f4 va, f4 vb, unsigned (&hi)[4]) {
  hi[0] = pack2(va[0], va[1]);
  hi[1] = pack2(va[2], va[3]);
  hi[2] = pack2(vb[0], vb[1]);
  hi[3] = pack2(vb[2], vb[3]);
}

// Load a single-plane bf16 A fragment (row fixed per lane).
__device__ __forceinline__ void loadAh(const float* W, int row, int g, unsigned (&hi)[4]) {
  const float* p = W + row * 32;
  f4 u = *(const f4*)(p + 4 * g);
  f4 v = *(const f4*)(p + 16 + 4 * g);
  hi[0] = pack2(u[0], u[1]);
  hi[1] = pack2(u[2], u[3]);
  hi[2] = pack2(v[0], v[1]);
  hi[3] = pack2(v[2], v[3]);
}

// 4-wave feed-forward pipeline, 8 timesteps per slot, 1 barrier per slot.
//   wave 0 (A): h1 recurrence (in regs)          -> LH1[m&1]   [2 MFMA/step]
//   wave 1 (D): P = Wih1@h1 + b1 (feed-forward)  -> LPp[m&1]   [2 MFMA/step, bf16-packed]
//   wave 2 (B): h2 = relu(P + Whh1@h2) (in regs) -> LB2[m&1]   [2 MFMA/step]
//   wave 3 (C): out = Wout.h2 + bO                             [1 MFMA/step]
// Skews: A slots [0,127], D [1,128], B [2,129], C [3,130].
__global__ __launch_bounds__(256) void rnn_fused(
    const float* __restrict__ x,    const float* __restrict__ h0,
    const float* __restrict__ Wih0, const float* __restrict__ Whh0,
    const float* __restrict__ bih0, const float* __restrict__ bhh0,
    const float* __restrict__ Wih1, const float* __restrict__ Whh1,
    const float* __restrict__ bih1, const float* __restrict__ bhh1,
    const float* __restrict__ Wout, const float* __restrict__ boutp,
    float* __restrict__ out)
{
  const int tid  = threadIdx.x;
  const int wid  = tid >> 6;
  const int lane = tid & 63;
  const int c = lane & 15;      // batch column within tile (also A-frag row)
  const int g = lane >> 4;      // lane group 0..3
  const int b = blockIdx.x * 16 + c;
  const unsigned li = (unsigned)lane * 4u;

  // b128-per-lane at lane*16B — conflict-free pattern (verified R6+). 48 KB.
  __shared__ unsigned LH1[2][SLOT][256];  // h1 frags   [parity][step j][u32]
  __shared__ unsigned LPp[2][SLOT][256];  // P bf16-packed: w0=P0[0,1] w1=P0[2,3] w2=P1[0,1] w3=P1[2,3]
  __shared__ unsigned LB2[2][SLOT][256];  // h2 frags

  const f4 z = {0.f, 0.f, 0.f, 0.f};
  float* hs = out + SEQ * BATCH;

  if (wid == 0) {
    // ================= WAVE A : layer 0 (h1 recurrence) =================
    unsigned W00h[4], W01h[4];
    loadAh(Whh0, c,      g, W00h);
    loadAh(Whh0, 16 + c, g, W01h);
    f4 wih0A, wih0B, b0A, b0B;
#pragma unroll
    for (int r = 0; r < 4; ++r) {
      int j0 = 4 * g + r, j1 = 16 + 4 * g + r;
      wih0A[r] = Wih0[j0];            wih0B[r] = Wih0[j1];
      b0A[r]   = bih0[j0] + bhh0[j0]; b0B[r]   = bih0[j1] + bhh0[j1];
    }
    unsigned B1h[4];
    {
      const float* p1 = h0 + b * 32;
      f4 u = *(const f4*)(p1 + 4 * g);
      f4 v = *(const f4*)(p1 + 16 + 4 * g);
      convh(u, v, B1h);
    }
    f4 v10 = z, v11 = z;
    float xc[SLOT];
#pragma unroll
    for (int j = 0; j < SLOT; ++j) xc[j] = x[j * BATCH + b];

#pragma unroll 1
    for (int m = 0; m < NSLOT; ++m) {
      if (m < SEQ / SLOT) {
        float xn[SLOT];
#pragma unroll
        for (int j = 0; j < SLOT; ++j) {
          int ti = SLOT * m + SLOT + j;
          xn[j] = x[(ti < SEQ ? ti : SEQ - 1) * BATCH + b];
        }
#pragma unroll
        for (int j = 0; j < SLOT; ++j) {
          float XV = xc[j];
          f4 c00, c01;
#pragma unroll
          for (int r = 0; r < 4; ++r) {
            c00[r] = fmaf(XV, wih0A[r], b0A[r]);
            c01[r] = fmaf(XV, wih0B[r], b0B[r]);
          }
          c00 = MF(W00h, B1h, c00);
          c01 = MF(W01h, B1h, c01);
#pragma unroll
          for (int r = 0; r < 4; ++r) {
            v10[r] = fmaxf(c00[r], 0.f);
            v11[r] = fmaxf(c01[r], 0.f);
          }
          convh(v10, v11, B1h);
          u4v wh = { B1h[0], B1h[1], B1h[2], B1h[3] };
          *(u4v*)&LH1[m & 1][j][li] = wh;
        }
#pragma unroll
        for (int j = 0; j < SLOT; ++j) xc[j] = xn[j];
      }
      __syncthreads();
    }
    *(f4*)(hs + b * 32 + 4 * g)      = v10;   // h1_SEQ
    *(f4*)(hs + b * 32 + 16 + 4 * g) = v11;

  } else if (wid == 1) {
    // ========== WAVE D : feeder P = Wih1 @ h1 + b1, bf16-packed out ==========
    unsigned WiH0[4], WiH1[4];
    loadAh(Wih1, c,      g, WiH0);
    loadAh(Wih1, 16 + c, g, WiH1);
    f4 b1A, b1B;
#pragma unroll
    for (int r = 0; r < 4; ++r) {
      int j0 = 4 * g + r, j1 = 16 + 4 * g + r;
      b1A[r] = bih1[j0] + bhh1[j0];
      b1B[r] = bih1[j1] + bhh1[j1];
    }

#pragma unroll 1
    for (int m = 0; m < NSLOT; ++m) {
      if (m >= 1 && m <= SEQ / SLOT) {
        int p = (m - 1) & 1;
        u4v fh[SLOT];
#pragma unroll
        for (int j = 0; j < SLOT; ++j)
          fh[j] = *(const u4v*)&LH1[p][j][li];
#pragma unroll
        for (int j = 0; j < SLOT; ++j) {
          unsigned B1h[4] = { fh[j][0], fh[j][1], fh[j][2], fh[j][3] };
          f4 P0 = MF(WiH0, B1h, b1A);
          f4 P1 = MF(WiH1, B1h, b1B);
          u4v wp = { permpack(P0[0], P0[1]), permpack(P0[2], P0[3]),
                     permpack(P1[0], P1[1]), permpack(P1[2], P1[3]) };
          *(u4v*)&LPp[m & 1][j][li] = wp;
        }
      }
      __syncthreads();
    }

  } else if (wid == 2) {
    // ========== WAVE B : h2 recurrence = relu(P + Whh1 @ h2) ==========
    unsigned WhH0[4], WhH1[4];
    loadAh(Whh1, c,      g, WhH0);
    loadAh(Whh1, 16 + c, g, WhH1);
    unsigned B2h[4];
    f4 v20 = z, v21 = z;
    {
      const float* p2 = h0 + BATCH * 32 + b * 32;
      f4 u = *(const f4*)(p2 + 4 * g);
      f4 v = *(const f4*)(p2 + 16 + 4 * g);
      convh(u, v, B2h);
      v20 = u; v21 = v;
    }

#pragma unroll 1
    for (int m = 0; m < NSLOT; ++m) {
      if (m >= 2 && m <= SEQ / SLOT + 1) {
        int p = (m - 1) & 1;
        u4v tw[SLOT];
#pragma unroll
        for (int j = 0; j < SLOT; ++j)
          tw[j] = *(const u4v*)&LPp[p][j][li];
#pragma unroll
        for (int j = 0; j < SLOT; ++j) {
          // explicit unpack matching permpack: low16 = elem0, high16 = elem1
          f4 Pa, Pb;
          Pa[0] = __uint_as_float(tw[j][0] << 16);
          Pa[1] = __uint_as_float(tw[j][0] & 0xffff0000u);
          Pa[2] = __uint_as_float(tw[j][1] << 16);
          Pa[3] = __uint_as_float(tw[j][1] & 0xffff0000u);
          Pb[0] = __uint_as_float(tw[j][2] << 16);
          Pb[1] = __uint_as_float(tw[j][2] & 0xffff0000u);
          Pb[2] = __uint_as_float(tw[j][3] << 16);
          Pb[3] = __uint_as_float(tw[j][3] & 0xffff0000u);
          f4 r0 = MF(WhH0, B2h, Pa);
          f4 s0 = MF(WhH1, B2h, Pb);
#pragma unroll
          for (int r = 0; r < 4; ++r) {
            v20[r] = fmaxf(r0[r], 0.f);
            v21[r] = fmaxf(s0[r], 0.f);
          }
          convh(v20, v21, B2h);
          u4v wh = { B2h[0], B2h[1], B2h[2], B2h[3] };
          *(u4v*)&LB2[m & 1][j][li] = wh;
        }
      }
      __syncthreads();
    }
    *(f4*)(hs + BATCH * 32 + b * 32 + 4 * g)      = v20;  // h2_SEQ
    *(f4*)(hs + BATCH * 32 + b * 32 + 16 + 4 * g) = v21;

  } else {
    // ================= WAVE C : output projection =================
    unsigned WOh[4];
    {
      f4 u = *(const f4*)(Wout + 4 * g);
      f4 v = *(const f4*)(Wout + 16 + 4 * g);
      convh(u, v, WOh);
    }
    const float bO = boutp[0];
    const f4 cb = { bO, bO, bO, bO };

#pragma unroll 1
    for (int m = 0; m < NSLOT; ++m) {
      if (m >= 3) {
        int p = (m - 1) & 1;
        u4v th[SLOT];
#pragma unroll
        for (int j = 0; j < SLOT; ++j)
          th[j] = *(const u4v*)&LB2[p][j][li];
#pragma unroll
        for (int j = 0; j < SLOT; ++j) {
          unsigned B2h[4] = { th[j][0], th[j][1], th[j][2], th[j][3] };
          f4 cO = MF(WOh, B2h, cb);
          int t = SLOT * (m - 3) + j;
          if (g == 0) out[t * BATCH + b] = cO[0];
        }
      }
      __syncthreads();
    }
  }
}

extern "C" void kernel_launch(void* const* d_in, const int* in_sizes, int n_in,
                              void* d_out, int out_size, void* d_ws, size_t ws_size,
                              hipStream_t stream) {
  rnn_fused<<<dim3(128), dim3(256), 0, stream>>>(
      (const float*)d_in[0],  (const float*)d_in[1],  (const float*)d_in[2],
      (const float*)d_in[3],  (const float*)d_in[4],  (const float*)d_in[5],
      (const float*)d_in[6],  (const float*)d_in[7],  (const float*)d_in[8],
      (const float*)d_in[9],  (const float*)d_in[10], (const float*)d_in[11],
      (float*)d_out);
}

// Round 13
// 122.967 us; speedup vs baseline: 2.2054x; 1.0680x over previous
//
#include <hip/hip_runtime.h>

typedef __attribute__((ext_vector_type(8))) short s8v;
typedef __attribute__((ext_vector_type(4))) float f4;
typedef __attribute__((ext_vector_type(4))) unsigned u4v;

#define SEQ 1024
#define BATCH 2048
#define SLOT 8
#define NSLOT (SEQ / SLOT + 3)   // 131

// RNE-pack two f32 into one u32 of 2 bf16 via v_cvt_pk_bf16_f32.
// Used ONLY for MFMA A/B fragments: the same packer builds both operands, so
// any within-pair order ambiguity applies the same k-permutation to A and B
// and cancels in the dot product (sigma-invariance).
__device__ __forceinline__ unsigned pack2(float a, float b) {
  unsigned r;
  asm("v_cvt_pk_bf16_f32 %0, %1, %2" : "=v"(r) : "v"(a), "v"(b));
  return r;
}

// DETERMINISTIC pack for LDS value storage (explicit unpack on the consumer
// side, so no sigma protection): low16 = bf16(a), high16 = bf16(b), with
// +0x8000 round-half-up. Verified layout (R7): perm selector 0x07060302.
__device__ __forceinline__ unsigned permpack(float a, float b) {
  unsigned au = __float_as_uint(a) + 0x8000u;
  unsigned bu = __float_as_uint(b) + 0x8000u;
  return __builtin_amdgcn_perm(bu, au, 0x07060302u);
}

__device__ __forceinline__ f4 MF(const unsigned (&a)[4], const unsigned (&b)[4], f4 c) {
  union U { unsigned u[4]; s8v v; } A, B;
  A.u[0] = a[0]; A.u[1] = a[1]; A.u[2] = a[2]; A.u[3] = a[3];
  B.u[0] = b[0]; B.u[1] = b[1]; B.u[2] = b[2]; B.u[3] = b[3];
  return __builtin_amdgcn_mfma_f32_16x16x32_bf16(A.v, B.v, c, 0, 0, 0);
}

// k-map (same on A and B operands so any mismatch with the true HW map
// cancels): elem i of lane-group g -> k = 4g+i (i<4), k = 16+4g+(i-4) (i>=4).
// C-layout (row = 4g + reg) feeds the next B-fragment with NO cross-lane moves.

// C-regs (va = rows 4g+r, vb = rows 16+4g+r) -> single-plane bf16 B-fragment.
__device__ __forceinline__ void convh(f4 va, f4 vb, unsigned (&hi)[4]) {
  hi[0] = pack2(va[0], va[1]);
  hi[1] = pack2(va[2], va[3]);
  hi[2] = pack2(vb[0], vb[1]);
  hi[3] = pack2(vb[2], vb[3]);
}

// Load a single-plane bf16 A fragment (row fixed per lane).
__device__ __forceinline__ void loadAh(const float* W, int row, int g, unsigned (&hi)[4]) {
  const float* p = W + row * 32;
  f4 u = *(const f4*)(p + 4 * g);
  f4 v = *(const f4*)(p + 16 + 4 * g);
  hi[0] = pack2(u[0], u[1]);
  hi[1] = pack2(u[2], u[3]);
  hi[2] = pack2(v[0], v[1]);
  hi[3] = pack2(v[2], v[3]);
}

// 4-wave feed-forward pipeline, 8 timesteps per slot, 1 barrier per slot.
//   wave 0 (A): h1 recurrence (in regs)          -> LH1[m&1]   [2 MFMA/step]
//   wave 1 (D): P = Wih1@h1 + b1 (feed-forward)  -> LPp[m&1]   [2 MFMA/step, bf16-packed]
//   wave 2 (B): h2 = relu(P + Whh1@h2) (in regs) -> LB2[m&1]   [2 MFMA/step]
//   wave 3 (C): out = Wout.h2 + bO                             [1 MFMA/step]
// Wave A's MFMAs are seeded with the CONSTANT bias (pre-issue dep chain = 0);
// the x-term is folded into the readout: v = relu(fmaf(x, wih0, acc)).
// Skews: A slots [0,127], D [1,128], B [2,129], C [3,130].
__global__ __launch_bounds__(256) void rnn_fused(
    const float* __restrict__ x,    const float* __restrict__ h0,
    const float* __restrict__ Wih0, const float* __restrict__ Whh0,
    const float* __restrict__ bih0, const float* __restrict__ bhh0,
    const float* __restrict__ Wih1, const float* __restrict__ Whh1,
    const float* __restrict__ bih1, const float* __restrict__ bhh1,
    const float* __restrict__ Wout, const float* __restrict__ boutp,
    float* __restrict__ out)
{
  const int tid  = threadIdx.x;
  const int wid  = tid >> 6;
  const int lane = tid & 63;
  const int c = lane & 15;      // batch column within tile (also A-frag row)
  const int g = lane >> 4;      // lane group 0..3
  const int b = blockIdx.x * 16 + c;
  const unsigned li = (unsigned)lane * 4u;

  // b128-per-lane at lane*16B — conflict-free pattern (verified R6+). 48 KB.
  __shared__ unsigned LH1[2][SLOT][256];  // h1 frags   [parity][step j][u32]
  __shared__ unsigned LPp[2][SLOT][256];  // P bf16-packed: w0=P0[0,1] w1=P0[2,3] w2=P1[0,1] w3=P1[2,3]
  __shared__ unsigned LB2[2][SLOT][256];  // h2 frags

  const f4 z = {0.f, 0.f, 0.f, 0.f};
  float* hs = out + SEQ * BATCH;

  if (wid == 0) {
    // ================= WAVE A : layer 0 (h1 recurrence) =================
    unsigned W00h[4], W01h[4];
    loadAh(Whh0, c,      g, W00h);
    loadAh(Whh0, 16 + c, g, W01h);
    f4 wih0A, wih0B, b0A, b0B;
#pragma unroll
    for (int r = 0; r < 4; ++r) {
      int j0 = 4 * g + r, j1 = 16 + 4 * g + r;
      wih0A[r] = Wih0[j0];            wih0B[r] = Wih0[j1];
      b0A[r]   = bih0[j0] + bhh0[j0]; b0B[r]   = bih0[j1] + bhh0[j1];
    }
    unsigned B1h[4];
    {
      const float* p1 = h0 + b * 32;
      f4 u = *(const f4*)(p1 + 4 * g);
      f4 v = *(const f4*)(p1 + 16 + 4 * g);
      convh(u, v, B1h);
    }
    f4 v10 = z, v11 = z;
    float xc[SLOT];
#pragma unroll
    for (int j = 0; j < SLOT; ++j) xc[j] = x[j * BATCH + b];

#pragma unroll 1
    for (int m = 0; m < NSLOT; ++m) {
      if (m < SEQ / SLOT) {
        float xn[SLOT];
#pragma unroll
        for (int j = 0; j < SLOT; ++j) {
          int ti = SLOT * m + SLOT + j;
          xn[j] = x[(ti < SEQ ? ti : SEQ - 1) * BATCH + b];
        }
#pragma unroll
        for (int j = 0; j < SLOT; ++j) {
          float XV = xc[j];
          // MFMAs issue immediately (C = constant bias, no pre-issue deps);
          // x-term is applied inside the readout-latency shadow.
          f4 c00 = MF(W00h, B1h, b0A);
          f4 c01 = MF(W01h, B1h, b0B);
#pragma unroll
          for (int r = 0; r < 4; ++r) {
            v10[r] = fmaxf(fmaf(XV, wih0A[r], c00[r]), 0.f);
            v11[r] = fmaxf(fmaf(XV, wih0B[r], c01[r]), 0.f);
          }
          convh(v10, v11, B1h);
          u4v wh = { B1h[0], B1h[1], B1h[2], B1h[3] };
          *(u4v*)&LH1[m & 1][j][li] = wh;
        }
#pragma unroll
        for (int j = 0; j < SLOT; ++j) xc[j] = xn[j];
      }
      __syncthreads();
    }
    *(f4*)(hs + b * 32 + 4 * g)      = v10;   // h1_SEQ
    *(f4*)(hs + b * 32 + 16 + 4 * g) = v11;

  } else if (wid == 1) {
    // ========== WAVE D : feeder P = Wih1 @ h1 + b1, bf16-packed out ==========
    unsigned WiH0[4], WiH1[4];
    loadAh(Wih1, c,      g, WiH0);
    loadAh(Wih1, 16 + c, g, WiH1);
    f4 b1A, b1B;
#pragma unroll
    for (int r = 0; r < 4; ++r) {
      int j0 = 4 * g + r, j1 = 16 + 4 * g + r;
      b1A[r] = bih1[j0] + bhh1[j0];
      b1B[r] = bih1[j1] + bhh1[j1];
    }

#pragma unroll 1
    for (int m = 0; m < NSLOT; ++m) {
      if (m >= 1 && m <= SEQ / SLOT) {
        int p = (m - 1) & 1;
        u4v fh[SLOT];
#pragma unroll
        for (int j = 0; j < SLOT; ++j)
          fh[j] = *(const u4v*)&LH1[p][j][li];
#pragma unroll
        for (int j = 0; j < SLOT; ++j) {
          unsigned B1h[4] = { fh[j][0], fh[j][1], fh[j][2], fh[j][3] };
          f4 P0 = MF(WiH0, B1h, b1A);
          f4 P1 = MF(WiH1, B1h, b1B);
          u4v wp = { permpack(P0[0], P0[1]), permpack(P0[2], P0[3]),
                     permpack(P1[0], P1[1]), permpack(P1[2], P1[3]) };
          *(u4v*)&LPp[m & 1][j][li] = wp;
        }
      }
      __syncthreads();
    }

  } else if (wid == 2) {
    // ========== WAVE B : h2 recurrence = relu(P + Whh1 @ h2) ==========
    unsigned WhH0[4], WhH1[4];
    loadAh(Whh1, c,      g, WhH0);
    loadAh(Whh1, 16 + c, g, WhH1);
    unsigned B2h[4];
    f4 v20 = z, v21 = z;
    {
      const float* p2 = h0 + BATCH * 32 + b * 32;
      f4 u = *(const f4*)(p2 + 4 * g);
      f4 v = *(const f4*)(p2 + 16 + 4 * g);
      convh(u, v, B2h);
      v20 = u; v21 = v;
    }

#pragma unroll 1
    for (int m = 0; m < NSLOT; ++m) {
      if (m >= 2 && m <= SEQ / SLOT + 1) {
        int p = (m - 1) & 1;
        u4v tw[SLOT];
#pragma unroll
        for (int j = 0; j < SLOT; ++j)
          tw[j] = *(const u4v*)&LPp[p][j][li];
#pragma unroll
        for (int j = 0; j < SLOT; ++j) {
          // explicit unpack matching permpack: low16 = elem0, high16 = elem1
          f4 Pa, Pb;
          Pa[0] = __uint_as_float(tw[j][0] << 16);
          Pa[1] = __uint_as_float(tw[j][0] & 0xffff0000u);
          Pa[2] = __uint_as_float(tw[j][1] << 16);
          Pa[3] = __uint_as_float(tw[j][1] & 0xffff0000u);
          Pb[0] = __uint_as_float(tw[j][2] << 16);
          Pb[1] = __uint_as_float(tw[j][2] & 0xffff0000u);
          Pb[2] = __uint_as_float(tw[j][3] << 16);
          Pb[3] = __uint_as_float(tw[j][3] & 0xffff0000u);
          f4 r0 = MF(WhH0, B2h, Pa);
          f4 s0 = MF(WhH1, B2h, Pb);
#pragma unroll
          for (int r = 0; r < 4; ++r) {
            v20[r] = fmaxf(r0[r], 0.f);
            v21[r] = fmaxf(s0[r], 0.f);
          }
          convh(v20, v21, B2h);
          u4v wh = { B2h[0], B2h[1], B2h[2], B2h[3] };
          *(u4v*)&LB2[m & 1][j][li] = wh;
        }
      }
      __syncthreads();
    }
    *(f4*)(hs + BATCH * 32 + b * 32 + 4 * g)      = v20;  // h2_SEQ
    *(f4*)(hs + BATCH * 32 + b * 32 + 16 + 4 * g) = v21;

  } else {
    // ================= WAVE C : output projection =================
    unsigned WOh[4];
    {
      f4 u = *(const f4*)(Wout + 4 * g);
      f4 v = *(const f4*)(Wout + 16 + 4 * g);
      convh(u, v, WOh);
    }
    const float bO = boutp[0];
    const f4 cb = { bO, bO, bO, bO };

#pragma unroll 1
    for (int m = 0; m < NSLOT; ++m) {
      if (m >= 3) {
        int p = (m - 1) & 1;
        u4v th[SLOT];
#pragma unroll
        for (int j = 0; j < SLOT; ++j)
          th[j] = *(const u4v*)&LB2[p][j][li];
#pragma unroll
        for (int j = 0; j < SLOT; ++j) {
          unsigned B2h[4] = { th[j][0], th[j][1], th[j][2], th[j][3] };
          f4 cO = MF(WOh, B2h, cb);
          int t = SLOT * (m - 3) + j;
          if (g == 0) out[t * BATCH + b] = cO[0];
        }
      }
      __syncthreads();
    }
  }
}

extern "C" void kernel_launch(void* const* d_in, const int* in_sizes, int n_in,
                              void* d_out, int out_size, void* d_ws, size_t ws_size,
                              hipStream_t stream) {
  rnn_fused<<<dim3(128), dim3(256), 0, stream>>>(
      (const float*)d_in[0],  (const float*)d_in[1],  (const float*)d_in[2],
      (const float*)d_in[3],  (const float*)d_in[4],  (const float*)d_in[5],
      (const float*)d_in[6],  (const float*)d_in[7],  (const float*)d_in[8],
      (const float*)d_in[9],  (const float*)d_in[10], (const float*)d_in[11],
      (float*)d_out);
}